// Round 1
// baseline (1342.606 us; speedup 1.0000x reference)
//
#include <hip/hip_runtime.h>

// Problem constants (from reference):
//   G = 500000 groups, N = 2000000 items, D = 128 feature dim, F = 8 map cols, FEAT = 0.
// Outputs (concatenated flat, fp32): x_pool (G*D) then x_seen (G) as 0.0/1.0.

#define D_DIM 128
#define F_COLS 8

// Kernel 1: one thread per group. Sequential scan of the CSR range with strict '>'
// reproduces the reference's (segment_max, then min-index-among-ties) exactly:
// same fp32 bit compares, no arithmetic. Empty group -> arg = n_items (zeros row).
__global__ void csr_argmax_kernel(const float* __restrict__ x_map,
                                  const int* __restrict__ csr_idx,
                                  int* __restrict__ arg_out,
                                  float* __restrict__ seen_out,
                                  int n_groups, int n_items) {
    int g = blockIdx.x * blockDim.x + threadIdx.x;
    if (g >= n_groups) return;
    int start = csr_idx[g];
    int end   = csr_idx[g + 1];
    float best = -INFINITY;
    int arg = n_items;                       // sentinel: empty group -> zeros row
    for (int i = start; i < end; ++i) {
        float v = x_map[(size_t)i * F_COLS]; // column FEAT=0, stride F
        if (v > best) { best = v; arg = i; } // strict > keeps FIRST max (tie-break min idx)
    }
    arg_out[g]  = arg;
    seen_out[g] = (end > start) ? 1.0f : 0.0f;
}

// Kernel 2: 32 lanes per group row; each lane moves one float4 (32 x 16 B = 512 B = one row).
// blockDim 256 -> 8 groups per block. arg indices are monotone through x_mod, so the
// gather is near-sequential -> good L2/HBM behavior.
__global__ void pool_gather_kernel(const float* __restrict__ x_mod,
                                   const int* __restrict__ arg_in,
                                   float* __restrict__ x_pool,
                                   int n_groups, int n_items) {
    int lane = threadIdx.x & 31;
    int g = blockIdx.x * (blockDim.x >> 5) + (threadIdx.x >> 5);
    if (g >= n_groups) return;
    int a = arg_in[g];
    float4 v = make_float4(0.f, 0.f, 0.f, 0.f);
    if (a < n_items) {
        v = ((const float4*)(x_mod + (size_t)a * D_DIM))[lane];
    }
    ((float4*)(x_pool + (size_t)g * D_DIM))[lane] = v;
}

extern "C" void kernel_launch(void* const* d_in, const int* in_sizes, int n_in,
                              void* d_out, int out_size, void* d_ws, size_t ws_size,
                              hipStream_t stream) {
    // Inputs in setup_inputs() order:
    //   d_in[0] = x_main (G*D fp32)  -- UNUSED by the reference
    //   d_in[1] = x_mod  (N*D fp32)
    //   d_in[2] = x_map  (N*F fp32)
    //   d_in[3] = csr_idx (G+1 int32)
    const float* x_mod   = (const float*)d_in[1];
    const float* x_map   = (const float*)d_in[2];
    const int*   csr_idx = (const int*)d_in[3];

    const int n_items  = in_sizes[1] / D_DIM;       // N = 2000000
    const int n_groups = in_sizes[3] - 1;           // G = 500000

    float* x_pool = (float*)d_out;                  // G*D floats
    float* x_seen = (float*)d_out + (size_t)n_groups * D_DIM; // G floats (0.0/1.0)

    int* arg_ws = (int*)d_ws;                       // G ints scratch

    {
        const int block = 256;
        const int grid = (n_groups + block - 1) / block;
        csr_argmax_kernel<<<grid, block, 0, stream>>>(x_map, csr_idx, arg_ws,
                                                      x_seen, n_groups, n_items);
    }
    {
        const int block = 256;                      // 8 groups per block
        const int grid = (n_groups + 7) / 8;
        pool_gather_kernel<<<grid, block, 0, stream>>>(x_mod, arg_ws, x_pool,
                                                       n_groups, n_items);
    }
}